// Round 7
// baseline (227.841 us; speedup 1.0000x reference)
//
#include <hip/hip_runtime.h>
#include <hip/hip_bf16.h>

typedef __bf16 bf16x8 __attribute__((ext_vector_type(8)));
typedef float  f32x4  __attribute__((ext_vector_type(4)));
typedef short  s16x4  __attribute__((ext_vector_type(4)));

#define QSCALE 0.25f
#define LOG2E  1.4426950408889634f

// f32 -> bf16 via compiler fptrunc (RNE); backend fuses pairs to v_cvt_pk_bf16_f32
static __device__ __forceinline__ unsigned short f2bf(float x) {
  union { __bf16 h; unsigned short u; } c;
  c.h = (__bf16)x;
  return c.u;
}
static __device__ __forceinline__ unsigned pk2(float a, float b) {
  union { __bf16 h[2]; unsigned u; } c;
  c.h[0] = (__bf16)a; c.h[1] = (__bf16)b;
  return c.u;
}
static __device__ __forceinline__ s16x4 mk4(unsigned w0, unsigned w1) {
  union { unsigned u[2]; s16x4 v; } c; c.u[0] = w0; c.u[1] = w1; return c.v;
}

// LDS tile rows of 128 B ([tok][ch] bf16); XOR-swizzle byte bits 4-6 by row&7.
#define SWZ(tk, ch2b) ((unsigned)((tk) * 128 + ((ch2b) ^ (((tk) & 7) << 4))))

// ---------------------------------------------------------------------------
// Prologue: weights -> bf16 MFMA fragments in d_ws (proven layout).
// For 16x16 shapes A-frag and B-frag lane maps coincide, so the same frags
// serve as A (transposed-proj) or B (normal-proj) operands.
// ---------------------------------------------------------------------------
__global__ void prep_weights(const float* __restrict__ wq, const float* __restrict__ wkv,
                             const float* __restrict__ wout, const float* __restrict__ bq,
                             const float* __restrict__ bkv, const float* __restrict__ bout,
                             unsigned* __restrict__ ws32) {
  const unsigned t = threadIdx.x;
  for (unsigned e = t; e < 2048; e += 256) {
    const unsigned fid = e >> 6, lane = e & 63;
    const unsigned l15 = lane & 15, g = lane >> 4;
    float v[8];
    if (fid < 8) {                     // WQ (scale*log2e folded)
      const unsigned nt = fid >> 1, kt = fid & 1, n = nt * 16 + l15;
#pragma unroll
      for (int i = 0; i < 8; ++i) v[i] = wq[(kt * 32 + g * 8 + i) * 64 + n] * (QSCALE * LOG2E);
    } else if (fid < 24) {             // WKV
      const unsigned f = fid - 8, nt = f >> 1, kt = f & 1, n = nt * 16 + l15;
#pragma unroll
      for (int i = 0; i < 8; ++i) v[i] = wkv[(kt * 32 + g * 8 + i) * 128 + n];
    } else {                           // WOUT^T: A[m=c_out][k=c_in] = wout[c_in][c_out]
      const unsigned f = fid - 24, mt = f >> 1, kt = f & 1, m = mt * 16 + l15;
#pragma unroll
      for (int i = 0; i < 8; ++i) v[i] = wout[(kt * 32 + g * 8 + i) * 64 + m];
    }
#pragma unroll
    for (int w = 0; w < 4; ++w) ws32[e * 4 + w] = pk2(v[2 * w], v[2 * w + 1]);
  }
  float* bws = (float*)(ws32 + 8192);
  if (t < 64)       bws[t] = bq[t] * (QSCALE * LOG2E);
  else if (t < 192) bws[t] = bkv[t - 64];
  else if (t < 256) bws[t] = bout[t - 192];
}

// ---------------------------------------------------------------------------
// Main: 1 block (4 waves) per 8x8 window; wave = head.
// LDS (16K): buf0 [0,8K) q window -> (after bar2) attn_out | buf1 [8K,16K) conv kv.
// Q^T/K^T/V projections' C-frags feed x16 attention MFMAs directly in-register
// (A/B lane maps == (l15, g*4+e)); only cross-head exchange (attn_out) uses LDS.
// ---------------------------------------------------------------------------
__launch_bounds__(256, 5)
__global__ void fused_win_attn(const float* __restrict__ qf, const float* __restrict__ kvf,
                               const float* __restrict__ wdw, const unsigned* __restrict__ ws32,
                               float* __restrict__ out) {
  __shared__ __align__(16) char lds[16384];
  unsigned short* lds16 = (unsigned short*)lds;
  unsigned* lds32p = (unsigned*)lds;

  // XCD-chunked swizzle
  const unsigned bid = blockIdx.x;
  const unsigned wid = (bid & 7) * 1024 + (bid >> 3);
  const unsigned b = wid >> 10, rem = wid & 1023;
  const unsigned y0 = (rem >> 5) * 8, x0 = (rem & 31) * 8;

  const unsigned t = threadIdx.x;
  const unsigned lane = t & 63;
  const unsigned wv = t >> 6;           // wave id = head id
  const unsigned l15 = lane & 15, g = lane >> 4;
  const unsigned tok = lane;            // edge conv: lane <-> token

  // ---- stage q window -> buf0: float4 loads, lane = channel ----
  {
    const float* qbase = qf + ((size_t)b * 64 + lane) * 65536 + (size_t)y0 * 256 + x0;
#pragma unroll
    for (int j = 0; j < 4; ++j) {
      const unsigned hr = (unsigned)j * 4 + wv;
      const unsigned row = hr >> 1, x4 = (hr & 1) * 4;
      const f32x4 v = *(const f32x4*)(qbase + row * 256 + x4);
#pragma unroll
      for (int i = 0; i < 4; ++i)
        lds16[SWZ(row * 8 + x4 + i, lane * 2) >> 1] = f2bf(v[i]);
    }
  }

  // ---- depthwise 3x3 conv (f32) -> buf1 ----
  const bool edge = (y0 == 0) || (y0 == 248) || (x0 == 0) || (x0 == 248);
  if (!edge) {
    // interior: 2 ch x 8 px (one window row) per thread; 4 float4 taps per (ch,row)
    const unsigned cp = t & 31, row = t >> 5;      // ch pair = 2cp, rows 0..7
    const float* kb0 = kvf + ((size_t)b * 64 + cp * 2) * 65536
                     + (size_t)(y0 + row - 1) * 256 + (x0 - 4);
    float acc[2][8];
#pragma unroll
    for (int c = 0; c < 2; ++c) {
      const float* cpl = kb0 + (size_t)c * 65536;
      float L[3][16];
#pragma unroll
      for (int dr = 0; dr < 3; ++dr)
#pragma unroll
        for (int s = 0; s < 4; ++s) {
          const f32x4 v = *(const f32x4*)(cpl + dr * 256 + s * 4);
          L[dr][s * 4 + 0] = v[0]; L[dr][s * 4 + 1] = v[1];
          L[dr][s * 4 + 2] = v[2]; L[dr][s * 4 + 3] = v[3];
        }
      const float* wp = wdw + (cp * 2 + (unsigned)c) * 9;
      float w[9];
#pragma unroll
      for (int k = 0; k < 9; ++k) w[k] = wp[k];
#pragma unroll
      for (int i = 0; i < 8; ++i) {
        float a = 0.f;
#pragma unroll
        for (int dr = 0; dr < 3; ++dr)
#pragma unroll
          for (int dx = 0; dx < 3; ++dx)
            a = fmaf(L[dr][i + 3 + dx], w[dr * 3 + dx], a);
        acc[c][i] = a;
      }
    }
#pragma unroll
    for (int i = 0; i < 8; ++i)
      lds32p[(8192u + SWZ(row * 8 + (unsigned)i, cp * 4)) >> 2] = pk2(acc[0][i], acc[1][i]);
  } else {
    // boundary: scalar clamped path (wave wv does ch [wv*16, wv*16+16))
    const int yy = (int)(y0 + (tok >> 3)), xx = (int)(x0 + (tok & 7));
    int off[9]; float msk[9];
#pragma unroll
    for (int dy = -1; dy <= 1; ++dy)
#pragma unroll
      for (int dx = -1; dx <= 1; ++dx) {
        const int k = (dy + 1) * 3 + (dx + 1);
        int yq = yy + dy, xq = xx + dx;
        const bool ok = (yq >= 0) && (yq < 256) && (xq >= 0) && (xq < 256);
        yq = yq < 0 ? 0 : (yq > 255 ? 255 : yq);
        xq = xq < 0 ? 0 : (xq > 255 ? 255 : xq);
        off[k] = yq * 256 + xq;
        msk[k] = ok ? 1.f : 0.f;
      }
    const float* kb = kvf + (size_t)b * 4194304 + (size_t)(wv * 16) * 65536;
    const float* wp0 = wdw + wv * 16 * 9;
#pragma unroll
    for (int c2 = 0; c2 < 8; ++c2) {
      float acc[2];
#pragma unroll
      for (int hh = 0; hh < 2; ++hh) {
        const float* cb = kb + (size_t)(c2 * 2 + hh) * 65536;
        const float* wp = wp0 + (c2 * 2 + hh) * 9;
        float a = 0.f;
#pragma unroll
        for (int k = 0; k < 9; ++k) a = fmaf(cb[off[k]], wp[k] * msk[k], a);
        acc[hh] = a;
      }
      lds32p[(8192u + SWZ(tok, (wv * 16 + c2 * 2) * 2)) >> 2] = pk2(acc[0], acc[1]);
    }
  }
  __syncthreads();  // barrier 1: staged q + conv visible

  const bf16x8* wsf = (const bf16x8*)ws32;
  const float* bws = (const float*)(ws32 + 8192);
  const f32x4 zero4 = (f32x4){0.f, 0.f, 0.f, 0.f};

  // ---- projections ----
  // q^T,K^T: C[m=ch_out(rows)][n=tok(l15)] = mfma(A=W_frag, B=win_frag)
  // V:       C[m=tok(rows)][n=ch(l15)]     = mfma(A=win_frag, B=W_frag)
  f32x4 qT[4], kT[4], vN[4];
  {
    const f32x4 bq4 = (f32x4){bws[wv * 16 + g * 4 + 0], bws[wv * 16 + g * 4 + 1],
                              bws[wv * 16 + g * 4 + 2], bws[wv * 16 + g * 4 + 3]};
    const f32x4 bk4 = (f32x4){bws[64 + wv * 16 + g * 4 + 0], bws[64 + wv * 16 + g * 4 + 1],
                              bws[64 + wv * 16 + g * 4 + 2], bws[64 + wv * 16 + g * 4 + 3]};
    const float bvv = bws[128 + wv * 16 + l15];
#pragma unroll
    for (int nt = 0; nt < 4; ++nt) {
      qT[nt] = bq4; kT[nt] = bk4;
      vN[nt] = (f32x4){bvv, bvv, bvv, bvv};
    }
#pragma unroll
    for (int kt = 0; kt < 2; ++kt) {
      const bf16x8 wqA = wsf[(wv * 2 + kt) * 64 + lane];
      const bf16x8 wkA = wsf[512 + (wv * 2 + kt) * 64 + lane];
      const bf16x8 wvB = wsf[512 + ((4 + wv) * 2 + kt) * 64 + lane];
#pragma unroll
      for (int nt = 0; nt < 4; ++nt) {
        const unsigned byo = SWZ(nt * 16 + l15, (kt * 32 + g * 8) * 2);
        const bf16x8 qF  = *(const bf16x8*)(lds + byo);
        const bf16x8 kvF = *(const bf16x8*)(lds + 8192 + byo);
        qT[nt] = __builtin_amdgcn_mfma_f32_16x16x32_bf16(wqA, qF,  qT[nt], 0, 0, 0);
        kT[nt] = __builtin_amdgcn_mfma_f32_16x16x32_bf16(wkA, kvF, kT[nt], 0, 0, 0);
        vN[nt] = __builtin_amdgcn_mfma_f32_16x16x32_bf16(kvF, wvB, vN[nt], 0, 0, 0);
      }
    }
  }
  __syncthreads();  // barrier 2: all buf0/buf1 reads done; buf0 may be overwritten

  // ---- pack C-frags as x16 A/B frags (in-lane; rows (g,r) <-> k-slots (g,e)) ----
  unsigned ka[4][2], qa[4][2], va[4][2];
#pragma unroll
  for (int t4 = 0; t4 < 4; ++t4) {
    ka[t4][0] = pk2(kT[t4][0], kT[t4][1]); ka[t4][1] = pk2(kT[t4][2], kT[t4][3]);
    qa[t4][0] = pk2(qT[t4][0], qT[t4][1]); qa[t4][1] = pk2(qT[t4][2], qT[t4][3]);
    va[t4][0] = pk2(vN[t4][0], vN[t4][1]); va[t4][1] = pk2(vN[t4][2], vN[t4][3]);
  }

  // ---- QK^T (x16, K=16 exact) + softmax + pack P, pipelined per tok1-tile ----
  float sinv[4];
  unsigned pp[4][4][2];   // [nt][mt][h]: P rows tok2=mt*16+g*4+{2h,2h+1}, col tok1=l15
#pragma unroll
  for (int nt = 0; nt < 4; ++nt) {
    f32x4 s[4];
#pragma unroll
    for (int mt = 0; mt < 4; ++mt)
      s[mt] = __builtin_amdgcn_mfma_f32_16x16x16bf16_1k(
          mk4(ka[mt][0], ka[mt][1]), mk4(qa[nt][0], qa[nt][1]), zero4, 0, 0, 0);
    float m = s[0][0];
#pragma unroll
    for (int mt = 0; mt < 4; ++mt)
#pragma unroll
      for (int r = 0; r < 4; ++r) m = fmaxf(m, s[mt][r]);
    m = fmaxf(m, __shfl_xor(m, 16));
    m = fmaxf(m, __shfl_xor(m, 32));
    float sum = 0.f;
#pragma unroll
    for (int mt = 0; mt < 4; ++mt)
#pragma unroll
      for (int r = 0; r < 4; ++r) {
        const float e = exp2f(s[mt][r] - m);
        s[mt][r] = e;
        sum += e;
      }
    sum += __shfl_xor(sum, 16);
    sum += __shfl_xor(sum, 32);
    sinv[nt] = 1.0f / sum;
#pragma unroll
    for (int mt = 0; mt < 4; ++mt) {
      pp[nt][mt][0] = pk2(s[mt][0], s[mt][1]);
      pp[nt][mt][1] = pk2(s[mt][2], s[mt][3]);
    }
  }

  // ---- PV (x16): out^T[ch_loc(rows)][tok1(l15)], K = tok2 (4 steps) ----
#pragma unroll
  for (int nt = 0; nt < 4; ++nt) {
    f32x4 o = zero4;
#pragma unroll
    for (int k2 = 0; k2 < 4; ++k2)
      o = __builtin_amdgcn_mfma_f32_16x16x16bf16_1k(
          mk4(va[k2][0], va[k2][1]), mk4(pp[nt][k2][0], pp[nt][k2][1]), o, 0, 0, 0);
#pragma unroll
    for (int r = 0; r < 4; ++r)
      lds16[SWZ(nt * 16 + l15, (wv * 16 + g * 4 + r) * 2) >> 1] = f2bf(o[r] * sinv[nt]);
  }
  __syncthreads();  // barrier 3: attn_out exchange

  // ---- output projection (x32): final^T[c_out][tok], wave owns c_out tile wv ----
  float bo[4];
#pragma unroll
  for (int r = 0; r < 4; ++r) bo[r] = bws[192 + wv * 16 + g * 4 + r];
  f32x4 facc[4];
#pragma unroll
  for (int nt = 0; nt < 4; ++nt) facc[nt] = (f32x4){bo[0], bo[1], bo[2], bo[3]};
#pragma unroll
  for (int kt = 0; kt < 2; ++kt) {
    const bf16x8 woA = wsf[1536 + (wv * 2 + kt) * 64 + lane];
#pragma unroll
    for (int nt = 0; nt < 4; ++nt) {
      const bf16x8 aB = *(const bf16x8*)(lds + SWZ(nt * 16 + l15, (kt * 32 + g * 8) * 2));
      facc[nt] = __builtin_amdgcn_mfma_f32_16x16x32_bf16(woA, aB, facc[nt], 0, 0, 0);
    }
  }
  float* ob = out + (size_t)b * 4194304 + (size_t)(wv * 16) * 65536 + (size_t)y0 * 256 + x0;
#pragma unroll
  for (int nt = 0; nt < 4; ++nt)
#pragma unroll
    for (int r = 0; r < 4; ++r) {
      const unsigned tk = nt * 16 + l15;
      ob[(size_t)(g * 4 + r) * 65536 + (tk >> 3) * 256 + (tk & 7)] = facc[nt][r];
    }
}

extern "C" void kernel_launch(void* const* d_in, const int* in_sizes, int n_in,
                              void* d_out, int out_size, void* d_ws, size_t ws_size,
                              hipStream_t stream) {
  const float* qf   = (const float*)d_in[0];
  const float* kvf  = (const float*)d_in[1];
  const float* wq   = (const float*)d_in[2];
  const float* bq   = (const float*)d_in[3];
  const float* wkv  = (const float*)d_in[4];
  const float* bkv  = (const float*)d_in[5];
  const float* wdw  = (const float*)d_in[6];
  const float* wout = (const float*)d_in[7];
  const float* bout = (const float*)d_in[8];
  (void)in_sizes; (void)n_in; (void)out_size; (void)ws_size;

  prep_weights<<<1, 256, 0, stream>>>(wq, wkv, wout, bq, bkv, bout, (unsigned*)d_ws);
  fused_win_attn<<<8192, 256, 0, stream>>>(qf, kvf, wdw, (const unsigned*)d_ws, (float*)d_out);
}